// Round 4
// baseline (55461.469 us; speedup 1.0000x reference)
//
#include <hip/hip_runtime.h>
#include <hip/hip_bf16.h>

#define TSTEPS 512
#define BATCH  128
#define DIM    512
#define HDIM   512
#define ODIM   256
#define N3     1536

// ---- ws layout (float offsets) ----
#define OFF_XT   1024      // xT  [256][128]
#define OFF_ST   33792     // sT  [512][128]
#define OFF_ZT   99328     // zT  [512][128]
#define OFF_RST  164864    // rsT [512][128]
#define OFF_PST  230400    // psT [512][128]
#define OFF_SUT  295936    // suT [1024][128]
#define OFF_WT   427008    // Wt   [1536][256]
#define OFF_UT1  820224    // Ut1  [1024][512]
#define OFF_UST  1344512   // Ust  [512][512]
#define OFF_WXOT 1606656   // Wxot [256][512]
#define OFF_HV   1737728   // bf16 [512][1536][128]

#define BAR_ROOT  512
#define BAR_EPOCH 528

__device__ __forceinline__ float sigmoid_(float a) {
  return 1.0f / (1.0f + __expf(-a));
}
__device__ __forceinline__ float tanh_(float a) {
  a = fminf(fmaxf(a, -30.0f), 30.0f);
  float e = __expf(2.0f * a);
  return (e - 1.0f) / (e + 1.0f);
}

// LLC-coherent state accessors (sc1, bypass incoherent per-XCD L2, no fences)
__device__ __forceinline__ float ld(const float* p) {
  return __hip_atomic_load((float*)p, __ATOMIC_RELAXED, __HIP_MEMORY_SCOPE_AGENT);
}
__device__ __forceinline__ void st(float* p, float v) {
  __hip_atomic_store(p, v, __ATOMIC_RELAXED, __HIP_MEMORY_SCOPE_AGENT);
}

// ---- one-time weight transposes into ws ----
__global__ void prep_kernel(const float* __restrict__ W, const float* __restrict__ U,
                            const float* __restrict__ Wx, float* __restrict__ ws) {
  int i = blockIdx.x * 256 + threadIdx.x;
  if (i < 393216) {                       // Wt[c][k] = W[k][c]
    int c = i >> 8, k = i & 255;
    ws[OFF_WT + i] = W[(size_t)k * N3 + c];
  } else if (i < 917504) {                // Ut1[c][k] = U[k][c], c<1024
    int j = i - 393216; int c = j >> 9, k = j & 511;
    ws[OFF_UT1 + j] = U[(size_t)k * N3 + c];
  } else if (i < 1179648) {               // Ust[c][k] = U[k][1024+c]
    int j = i - 917504; int c = j >> 9, k = j & 511;
    ws[OFF_UST + j] = U[(size_t)k * N3 + 1024 + c];
  } else if (i < 1310720) {               // Wxot[c][k] = W_x[k][c], c<256
    int j = i - 1179648; int c = j >> 9, k = j & 511;
    ws[OFF_WXOT + j] = Wx[(size_t)k * 768 + c];
  }
}

// ---- state init ----
__global__ void init_kernel(const float* __restrict__ H, float* __restrict__ ws) {
  int i = blockIdx.x * 256 + threadIdx.x;   // grid 512 -> 131072
  if (i < 1024) ((unsigned*)ws)[i] = 0u;                 // barrier region
  if (i < 65536) ws[OFF_ST + i] = 0.0f;
  if (i < 131072) ws[OFF_SUT + i] = 0.0f;
  if (i < 32768) {
    int c = i >> 7, b = i & 127;
    const float* hrow = H + ((size_t)b * TSTEPS + (TSTEPS - 1)) * DIM;
    ws[OFF_XT + i] = hrow[c] + hrow[c + ODIM];
  }
}

// ---- hv precompute, transposed bf16 store: hvT[t][c][b] ----
__global__ void hv_kernel(const float* __restrict__ H,
                          const float* __restrict__ Vr,
                          const float* __restrict__ Vz,
                          const float* __restrict__ Vs,
                          __hip_bfloat16* __restrict__ hvT) {
  __shared__ float tile[64 * 33];
  int c  = threadIdx.x & 63;
  int q  = threadIdx.x >> 6;
  int i0 = blockIdx.x * 32;
  int l  = i0 >> 7;
  int b0 = i0 & 127;
  int n0 = blockIdx.y * 64;
  int seg = n0 >> 9;
  int jj  = (n0 & 511) + c;
  const float* V = (seg == 0) ? Vr : ((seg == 1) ? Vz : Vs);

  const float* Arow[8];
  #pragma unroll
  for (int rr = 0; rr < 8; ++rr) {
    int b = b0 + q + rr * 4;
    Arow[rr] = H + ((size_t)b * TSTEPS + (TSTEPS - 1 - l)) * DIM;
  }
  float acc[8];
  #pragma unroll
  for (int rr = 0; rr < 8; ++rr) acc[rr] = 0.0f;

  for (int k = 0; k < DIM; k += 4) {
    float v0 = V[(size_t)(k + 0) * HDIM + jj];
    float v1 = V[(size_t)(k + 1) * HDIM + jj];
    float v2 = V[(size_t)(k + 2) * HDIM + jj];
    float v3 = V[(size_t)(k + 3) * HDIM + jj];
    #pragma unroll
    for (int rr = 0; rr < 8; ++rr) {
      float4 a = *(const float4*)(Arow[rr] + k);
      acc[rr] = fmaf(a.x, v0, acc[rr]);
      acc[rr] = fmaf(a.y, v1, acc[rr]);
      acc[rr] = fmaf(a.z, v2, acc[rr]);
      acc[rr] = fmaf(a.w, v3, acc[rr]);
    }
  }
  #pragma unroll
  for (int rr = 0; rr < 8; ++rr) tile[c * 33 + q + 4 * rr] = acc[rr];
  __syncthreads();
  #pragma unroll
  for (int i = 0; i < 8; ++i) {
    int lin = i * 256 + threadIdx.x;
    int cc = lin >> 5, bb = lin & 31;
    hvT[((size_t)l * N3 + n0 + cc) * 128 + b0 + bb] = __float2bfloat16(tile[cc * 33 + bb]);
  }
}

// ---- fence-free monotonic grid barrier: 32 groups x 16 blocks ----
__device__ __forceinline__ void grid_barrier(unsigned* bar, unsigned ep) {
  asm volatile("s_waitcnt vmcnt(0)" ::: "memory");  // every wave drains its own stores
  __syncthreads();
  if (threadIdx.x == 0) {
    unsigned gslot = (blockIdx.x >> 4) << 4;     // slots 0,16,...,496 (64B apart)
    if (__hip_atomic_fetch_add(&bar[gslot], 1u, __ATOMIC_RELAXED, __HIP_MEMORY_SCOPE_AGENT) == ep * 16u - 1u) {
      if (__hip_atomic_fetch_add(&bar[BAR_ROOT], 1u, __ATOMIC_RELAXED, __HIP_MEMORY_SCOPE_AGENT) == ep * 32u - 1u) {
        __hip_atomic_store(&bar[BAR_EPOCH], ep, __ATOMIC_RELAXED, __HIP_MEMORY_SCOPE_AGENT);
      } else {
        while (__hip_atomic_load(&bar[BAR_EPOCH], __ATOMIC_RELAXED, __HIP_MEMORY_SCOPE_AGENT) < ep) {}
      }
    } else {
      while (__hip_atomic_load(&bar[BAR_EPOCH], __ATOMIC_RELAXED, __HIP_MEMORY_SCOPE_AGENT) < ep) {}
    }
  }
  __syncthreads();
}

// ---- persistent scan: 512 blocks x 256 threads (2 blocks/CU guaranteed) ----
__global__ __launch_bounds__(256, 2) void scan_kernel(
    const float* __restrict__ Bb, const float* __restrict__ b_x,
    float* __restrict__ ws, float* __restrict__ out)
{
  __shared__ float parts[12 * 8 * 32];   // 12KB, reused by all phases

  float* xT  = ws + OFF_XT;
  float* sT  = ws + OFF_ST;
  float* zT  = ws + OFF_ZT;
  float* rsT = ws + OFF_RST;
  float* psT = ws + OFF_PST;
  float* suT = ws + OFF_SUT;
  const float* Wt   = ws + OFF_WT;
  const float* Ut1  = ws + OFF_UT1;
  const float* Ust  = ws + OFF_UST;
  const float* Wxot = ws + OFF_WXOT;
  const __hip_bfloat16* hvT = (const __hip_bfloat16*)(ws + OFF_HV);
  unsigned* bar = (unsigned*)ws;

  const int tid = threadIdx.x;
  const int bid = blockIdx.x;
  const int cg  = bid >> 2;          // 0..127 column-group
  const int rg  = bid & 3;           // 0..3 row-group
  const int row = tid & 31;
  const int g   = tid >> 5;          // 0..7 K-partition group
  const int b   = rg * 32 + row;     // batch row

  unsigned ep = 0;

  for (int t = 0; t < TSTEPS; ++t) {
    // ========== Phase 1: gates. cols [cg*12, cg*12+12), K=256 split 8x32 ==========
    {
      float xk[32];
      #pragma unroll
      for (int j = 0; j < 32; ++j)
        xk[j] = ld(xT + (size_t)(g * 32 + j) * 128 + b);

      const int colA = cg * 12 + g;          // combine slot A (all g)
      const int colB = cg * 12 + 8 + g;      // combine slot B (g<4)
      float bbA = Bb[colA];
      float hvA = __bfloat162float(hvT[((size_t)t * N3 + colA) * 128 + b]);
      float suA = (colA < 1024) ? ld(suT + (size_t)colA * 128 + b) : 0.0f;
      float sA_ = (colA < 512)  ? ld(sT  + (size_t)colA * 128 + b) : 0.0f;
      float bbB = 0.0f, hvB = 0.0f, suB = 0.0f, sB_ = 0.0f;
      if (g < 4) {
        bbB = Bb[colB];
        hvB = __bfloat162float(hvT[((size_t)t * N3 + colB) * 128 + b]);
        suB = (colB < 1024) ? ld(suT + (size_t)colB * 128 + b) : 0.0f;
        sB_ = (colB < 512)  ? ld(sT  + (size_t)colB * 128 + b) : 0.0f;
      }

      float acc[12];
      #pragma unroll
      for (int c = 0; c < 12; ++c) acc[c] = 0.0f;
      const float* wb = Wt + (size_t)(cg * 12) * 256 + g * 32;
      #pragma unroll
      for (int j4 = 0; j4 < 8; ++j4) {
        #pragma unroll
        for (int c = 0; c < 12; ++c) {
          float4 w = *(const float4*)(wb + (size_t)c * 256 + j4 * 4);
          acc[c] = fmaf(xk[j4 * 4 + 0], w.x, acc[c]);
          acc[c] = fmaf(xk[j4 * 4 + 1], w.y, acc[c]);
          acc[c] = fmaf(xk[j4 * 4 + 2], w.z, acc[c]);
          acc[c] = fmaf(xk[j4 * 4 + 3], w.w, acc[c]);
        }
      }
      #pragma unroll
      for (int c = 0; c < 12; ++c) parts[(c * 8 + g) * 32 + row] = acc[c];
      __syncthreads();
      {
        float sum = 0.0f;
        #pragma unroll
        for (int gg = 0; gg < 8; ++gg) sum += parts[(g * 8 + gg) * 32 + row];
        float pre = sum + bbA + hvA + suA;
        if (colA < 512)       st(rsT + (size_t)colA * 128 + b, sigmoid_(pre) * sA_);
        else if (colA < 1024) st(zT + (size_t)(colA - 512) * 128 + b, sigmoid_(pre));
        else                  st(psT + (size_t)(colA - 1024) * 128 + b, pre);
      }
      if (g < 4) {
        float sum = 0.0f;
        #pragma unroll
        for (int gg = 0; gg < 8; ++gg) sum += parts[((8 + g) * 8 + gg) * 32 + row];
        float pre = sum + bbB + hvB + suB;
        if (colB < 512)       st(rsT + (size_t)colB * 128 + b, sigmoid_(pre) * sB_);
        else if (colB < 1024) st(zT + (size_t)(colB - 512) * 128 + b, sigmoid_(pre));
        else                  st(psT + (size_t)(colB - 1024) * 128 + b, pre);
      }
    }
    grid_barrier(bar, ++ep);

    // ========== Phase 2: s update. cols [cg*4, cg*4+4), K=512 split 8x64 ==========
    {
      float rk[64];
      #pragma unroll
      for (int j = 0; j < 64; ++j)
        rk[j] = ld(rsT + (size_t)(g * 64 + j) * 128 + b);

      const int h2 = cg * 4 + g;             // valid for g<4
      float p_ps = 0.0f, p_z = 0.0f, p_s = 0.0f;
      if (g < 4) {
        p_ps = ld(psT + (size_t)h2 * 128 + b);
        p_z  = ld(zT  + (size_t)h2 * 128 + b);
        p_s  = ld(sT  + (size_t)h2 * 128 + b);
      }

      float acc2[4] = {0.0f, 0.0f, 0.0f, 0.0f};
      const float* ub = Ust + (size_t)(cg * 4) * 512 + g * 64;
      #pragma unroll
      for (int j4 = 0; j4 < 16; ++j4) {
        #pragma unroll
        for (int c = 0; c < 4; ++c) {
          float4 w = *(const float4*)(ub + (size_t)c * 512 + j4 * 4);
          acc2[c] = fmaf(rk[j4 * 4 + 0], w.x, acc2[c]);
          acc2[c] = fmaf(rk[j4 * 4 + 1], w.y, acc2[c]);
          acc2[c] = fmaf(rk[j4 * 4 + 2], w.z, acc2[c]);
          acc2[c] = fmaf(rk[j4 * 4 + 3], w.w, acc2[c]);
        }
      }
      #pragma unroll
      for (int c = 0; c < 4; ++c) parts[(c * 8 + g) * 32 + row] = acc2[c];
      __syncthreads();
      if (g < 4) {
        float sum = 0.0f;
        #pragma unroll
        for (int gg = 0; gg < 8; ++gg) sum += parts[(g * 8 + gg) * 32 + row];
        float s1 = tanh_(p_ps + sum);
        st(sT + (size_t)h2 * 128 + b, p_s + p_z * (s1 - p_s));
      }
    }
    grid_barrier(bar, ++ep);

    // ========== Phase 3: su lookahead (8 cols) + x out (2 cols). K=512 split 8x64 ==========
    {
      float sk[64];
      #pragma unroll
      for (int j = 0; j < 64; ++j)
        sk[j] = ld(sT + (size_t)(g * 64 + j) * 128 + b);

      float acc3[10];
      #pragma unroll
      for (int c = 0; c < 10; ++c) acc3[c] = 0.0f;
      const float* u1b = Ut1  + (size_t)(cg * 8) * 512 + g * 64;
      const float* wxb = Wxot + (size_t)(cg * 2) * 512 + g * 64;
      #pragma unroll
      for (int j4 = 0; j4 < 16; ++j4) {
        #pragma unroll
        for (int c = 0; c < 8; ++c) {
          float4 w = *(const float4*)(u1b + (size_t)c * 512 + j4 * 4);
          acc3[c] = fmaf(sk[j4 * 4 + 0], w.x, acc3[c]);
          acc3[c] = fmaf(sk[j4 * 4 + 1], w.y, acc3[c]);
          acc3[c] = fmaf(sk[j4 * 4 + 2], w.z, acc3[c]);
          acc3[c] = fmaf(sk[j4 * 4 + 3], w.w, acc3[c]);
        }
        #pragma unroll
        for (int c = 0; c < 2; ++c) {
          float4 w = *(const float4*)(wxb + (size_t)c * 512 + j4 * 4);
          acc3[8 + c] = fmaf(sk[j4 * 4 + 0], w.x, acc3[8 + c]);
          acc3[8 + c] = fmaf(sk[j4 * 4 + 1], w.y, acc3[8 + c]);
          acc3[8 + c] = fmaf(sk[j4 * 4 + 2], w.z, acc3[8 + c]);
          acc3[8 + c] = fmaf(sk[j4 * 4 + 3], w.w, acc3[8 + c]);
        }
      }
      #pragma unroll
      for (int c = 0; c < 10; ++c) parts[(c * 8 + g) * 32 + row] = acc3[c];
      __syncthreads();
      {
        float sum = 0.0f;
        #pragma unroll
        for (int gg = 0; gg < 8; ++gg) sum += parts[(g * 8 + gg) * 32 + row];
        st(suT + (size_t)(cg * 8 + g) * 128 + b, sum);
      }
      if (g < 2) {
        float sum = 0.0f;
        #pragma unroll
        for (int gg = 0; gg < 8; ++gg) sum += parts[((8 + g) * 8 + gg) * 32 + row];
        int xc = cg * 2 + g;
        float xv = tanh_(sum + b_x[xc]);
        st(xT + (size_t)xc * 128 + b, xv);
        out[((size_t)b * TSTEPS + t) * ODIM + xc] = xv;
      }
    }
    grid_barrier(bar, ++ep);
  }
}

extern "C" void kernel_launch(void* const* d_in, const int* in_sizes, int n_in,
                              void* d_out, int out_size, void* d_ws, size_t ws_size,
                              hipStream_t stream) {
  const float* H   = (const float*)d_in[0];
  const float* W   = (const float*)d_in[1];
  const float* Bb  = (const float*)d_in[2];
  const float* U   = (const float*)d_in[3];
  const float* W_x = (const float*)d_in[4];
  const float* b_x = (const float*)d_in[5];
  const float* Vr  = (const float*)d_in[6];
  const float* Vz  = (const float*)d_in[7];
  const float* Vs  = (const float*)d_in[8];
  float* out = (float*)d_out;
  float* ws  = (float*)d_ws;
  __hip_bfloat16* hvT = (__hip_bfloat16*)(ws + OFF_HV);

  prep_kernel<<<5120, 256, 0, stream>>>(W, U, W_x, ws);
  init_kernel<<<512, 256, 0, stream>>>(H, ws);
  hv_kernel<<<dim3(2048, 24), 256, 0, stream>>>(H, Vr, Vz, Vs, hvT);
  scan_kernel<<<512, 256, 0, stream>>>(Bb, b_x, ws, out);
}